// Round 7
// baseline (334.201 us; speedup 1.0000x reference)
//
#include <hip/hip_runtime.h>
#include <cstdint>
#include <cstddef>

typedef __bf16 bf16;
typedef __attribute__((ext_vector_type(8))) __bf16 bf16x8;
typedef __attribute__((ext_vector_type(4))) __bf16 bf16x4;
typedef __attribute__((ext_vector_type(2))) __bf16 bf16x2;
typedef __attribute__((ext_vector_type(4))) float f32x4;

#define MFMA_16x16x32(a, b, c) __builtin_amdgcn_mfma_f32_16x16x32_bf16((a), (b), (c), 0, 0, 0)

__device__ __forceinline__ void gload_lds16(const void* g, void* l) {
  __builtin_amdgcn_global_load_lds((__attribute__((address_space(1))) void*)g,
                                   (__attribute__((address_space(3))) void*)l,
                                   16, 0, 0);
}

// ---------------------------------------------------------------------------
// fp32 -> bf16 convert (grid covers exactly n/4 elements, n = 4096*1024)
// ---------------------------------------------------------------------------
__global__ __launch_bounds__(256) void cvt_x_kernel(const float* __restrict__ in,
                                                    bf16* __restrict__ out) {
  int i = blockIdx.x * 256 + threadIdx.x;
  float4 v = ((const float4*)in)[i];
  bf16x4 o = {(bf16)v.x, (bf16)v.y, (bf16)v.z, (bf16)v.w};
  ((bf16x4*)out)[i] = o;
}

// ---------------------------------------------------------------------------
// transpose + convert: in fp32 [R][C] -> out bf16 [C][R]
// ---------------------------------------------------------------------------
__global__ __launch_bounds__(256) void transpose_cvt_kernel(const float* __restrict__ in,
                                                            bf16* __restrict__ out,
                                                            int R, int C) {
  __shared__ float tile[32][33];
  int tiles_c = C >> 5;
  int br = (int)blockIdx.x / tiles_c, bc = (int)blockIdx.x % tiles_c;
  int r0 = br << 5, c0 = bc << 5;
  int tr = threadIdx.x >> 5, tc = threadIdx.x & 31;
#pragma unroll
  for (int i = 0; i < 4; i++)
    tile[tr + 8 * i][tc] = in[(size_t)(r0 + tr + 8 * i) * C + c0 + tc];
  __syncthreads();
#pragma unroll
  for (int i = 0; i < 4; i++) {
    int oc = tr + 8 * i;
    out[(size_t)(c0 + oc) * R + r0 + tc] = (bf16)tile[tc][oc];
  }
}

// ---------------------------------------------------------------------------
// Fused QKV projection GEMM, 256x256 tile, 8-phase counted-vmcnt schedule.
// A [4096][1024] bf16; Bt [9216][1024] bf16 = Wq^T | Wv^T | Wk^T contiguous.
// Out: seg0 -> Qm (+q_b), seg1 -> Km (+v_b), seg2 -> Vt transposed (+k_b).
// 512 thr = 8 waves (2M x 4N); per-wave out 128x64 (acc[8][4] f32x4).
// LDS [buf][khalf][256][32] bf16: each gload region = 16 rows x 64B linear;
// 64B rows make ds_read_b128 conflict-minimal without swizzle.
// Phase: {ds_read frags; stage 1 region; [vmcnt(6) even ph]; s_barrier;
//         lgkmcnt(0)+sched_barrier; setprio(1); 16 MFMA; setprio(0)}.
// Staging slots: ph1 B-kh0(s+1), ph2 A-kh1(s+1), ph3 B-kh1(s+1),
// ph4 A-kh0(s+2). All regions' last read >=2 phases before restage.
// vmcnt(6) at ph2 gates kh1(s) (read ph3); at ph4 gates kh0(s+1) (read ph1').
// ---------------------------------------------------------------------------
__global__ __launch_bounds__(512, 2) void gemm_fused_qkv(
    const bf16* __restrict__ A, const bf16* __restrict__ Bt,
    const float* __restrict__ q_b, const float* __restrict__ v_b,
    const float* __restrict__ k_b,
    bf16* __restrict__ Qm, bf16* __restrict__ Km, bf16* __restrict__ Vt) {
  constexpr int K = 1024, NT = 16;  // K-tiles of 64
  __shared__ __align__(16) bf16 sA[2][2][256 * 32];
  __shared__ __align__(16) bf16 sB[2][2][256 * 32];

  // XCD swizzle: 576 blocks, 72/XCD, bn-major within an XCD (B-panel L2 reuse)
  int bid = blockIdx.x;
  int swz = (bid & 7) * 72 + (bid >> 3);
  int bm = swz & 15, bn = swz >> 4;
  int m0 = bm << 8, n0 = bn << 8;

  int tid = threadIdx.x, lane = tid & 63, w = tid >> 6;
  int wr = w >> 2, wc = w & 3;
  int l15 = lane & 15, lg = lane >> 4;

  // staging lane geometry: region = 16 rows x 4 chunks of 16B
  int srow = lane >> 2, schk = lane & 3;
  const bf16* gA = A + (size_t)(m0 + w * 32 + srow) * K + schk * 8;
  const bf16* gB = Bt + (size_t)(n0 + w * 32 + srow) * K + schk * 8;
  int ldsR = (w * 32) * 32;  // wave's region base (elems) within [256][32]

#define STAGE_A(BUF, KH, T)                                                   \
  {                                                                           \
    _Pragma("unroll") for (int ii = 0; ii < 2; ii++)                          \
        gload_lds16(gA + (size_t)(ii * 16) * K + (T) * 64 + (KH) * 32,        \
                    &sA[BUF][KH][ldsR + ii * 512]);                           \
  }
#define STAGE_B(BUF, KH, T)                                                   \
  {                                                                           \
    _Pragma("unroll") for (int ii = 0; ii < 2; ii++)                          \
        gload_lds16(gB + (size_t)(ii * 16) * K + (T) * 64 + (KH) * 32,        \
                    &sB[BUF][KH][ldsR + ii * 512]);                           \
  }
#define VMCNT6 asm volatile("s_waitcnt vmcnt(6)" ::: "memory")
#define LGK0                                           \
  {                                                    \
    asm volatile("s_waitcnt lgkmcnt(0)" ::: "memory"); \
    __builtin_amdgcn_sched_barrier(0);                 \
  }

  int aOff = (wr * 128 + l15) * 32 + lg * 8;
  int bOff = (wc * 64 + l15) * 32 + lg * 8;

#define RD_A(BUF, KS, MFB)                                                 \
  _Pragma("unroll") for (int mf = 0; mf < 4; mf++)                         \
      a[mf] = *(const bf16x8*)&sA[BUF][KS][aOff + (MFB + mf) * 512];
#define RD_B(BUF, KS, BV)                                                  \
  _Pragma("unroll") for (int nf = 0; nf < 4; nf++)                         \
      BV[nf] = *(const bf16x8*)&sB[BUF][KS][bOff + nf * 512];
#define MFMA_BLK(MFB, BV)                                                  \
  _Pragma("unroll") for (int mf = 0; mf < 4; mf++)                         \
      _Pragma("unroll") for (int nf = 0; nf < 4; nf++)                     \
          acc[MFB + mf][nf] = MFMA_16x16x32(a[mf], BV[nf], acc[MFB + mf][nf]);

  f32x4 acc[8][4];
#pragma unroll
  for (int mf = 0; mf < 8; mf++)
#pragma unroll
    for (int nf = 0; nf < 4; nf++) acc[mf][nf] = (f32x4){0.f, 0.f, 0.f, 0.f};

  // prologue: A-kh0(0), B-kh0(0), A-kh1(0), B-kh1(0), A-kh0(1)  (10 loads/wave)
  STAGE_A(0, 0, 0);
  STAGE_B(0, 0, 0);
  STAGE_A(0, 1, 0);
  STAGE_B(0, 1, 0);
  STAGE_A(1, 0, 1);
  VMCNT6;  // oldest 4 (= kh0(0)) landed
  __builtin_amdgcn_s_barrier();

#pragma unroll 2
  for (int s = 0; s < NT; s++) {
    int buf = s & 1, nbuf = buf ^ 1;
    int nxt = (s + 1) & (NT - 1), nx2 = (s + 2) & (NT - 1);
    bf16x8 a[4], b0[4], b1[4];

    // ---- ph1: ks0, mf0-3
    RD_A(buf, 0, 0);
    RD_B(buf, 0, b0);
    STAGE_B(nbuf, 0, nxt);
    __builtin_amdgcn_s_barrier();
    LGK0;
    __builtin_amdgcn_s_setprio(1);
    MFMA_BLK(0, b0);
    __builtin_amdgcn_s_setprio(0);

    // ---- ph2: ks0, mf4-7
    RD_A(buf, 0, 4);
    STAGE_A(nbuf, 1, nxt);
    VMCNT6;  // gates kh1(s) for ph3 (cross-wave via barrier)
    __builtin_amdgcn_s_barrier();
    LGK0;
    __builtin_amdgcn_s_setprio(1);
    MFMA_BLK(4, b0);
    __builtin_amdgcn_s_setprio(0);

    // ---- ph3: ks1, mf0-3
    RD_A(buf, 1, 0);
    RD_B(buf, 1, b1);
    STAGE_B(nbuf, 1, nxt);
    __builtin_amdgcn_s_barrier();
    LGK0;
    __builtin_amdgcn_s_setprio(1);
    MFMA_BLK(0, b1);
    __builtin_amdgcn_s_setprio(0);

    // ---- ph4: ks1, mf4-7
    RD_A(buf, 1, 4);
    STAGE_A(buf, 0, nx2);
    VMCNT6;  // gates kh0(s+1) for next ph1
    __builtin_amdgcn_s_barrier();
    LGK0;
    __builtin_amdgcn_s_setprio(1);
    MFMA_BLK(4, b1);
    __builtin_amdgcn_s_setprio(0);
  }

  // ---- epilogue: route by N-segment (block-uniform; 3072 % 256 == 0)
  int seg = bn / 12;
  int segbn = bn - seg * 12;
  const float* bias = seg == 0 ? q_b : (seg == 1 ? v_b : k_b);
  bf16* outQK = seg == 0 ? Qm : Km;
#pragma unroll
  for (int mf = 0; mf < 8; mf++) {
#pragma unroll
    for (int nf = 0; nf < 4; nf++) {
      int colL = segbn * 256 + wc * 64 + nf * 16 + l15;
      int row0 = m0 + wr * 128 + mf * 16 + lg * 4;
      float bv = bias[colL];
      if (seg < 2) {
#pragma unroll
        for (int r = 0; r < 4; r++)
          outQK[(size_t)(row0 + r) * 3072 + colL] = (bf16)(acc[mf][nf][r] + bv);
      } else {
        int hh = colL / 192, dd = colL % 192;
        int bi = row0 >> 11, nn = row0 & 2047;
        bf16x4 pk = {(bf16)(acc[mf][nf][0] + bv), (bf16)(acc[mf][nf][1] + bv),
                     (bf16)(acc[mf][nf][2] + bv), (bf16)(acc[mf][nf][3] + bv)};
        *(bf16x4*)(Vt + (((size_t)bi * 16 + hh) * 192 + dd) * 2048 + nn) = pk;
      }
    }
  }
#undef STAGE_A
#undef STAGE_B
#undef VMCNT6
#undef LGK0
#undef RD_A
#undef RD_B
#undef MFMA_BLK
}

// ---------------------------------------------------------------------------
// bf16 GEMM (m97 structure), used for the final output projection.
// C[m][n] = sum_k A[m][k] * Bt[n][k] + bias[n]; fp32 out [M][N].
// ---------------------------------------------------------------------------
template <int EPI>
__global__ __launch_bounds__(256, 2) void gemm_bf16_kernel(const bf16* __restrict__ A,
                                                           const bf16* __restrict__ Bt,
                                                           const float* __restrict__ bias,
                                                           void* __restrict__ Cout,
                                                           int M, int N, int K) {
  __shared__ __align__(16) bf16 sA[128 * 64];
  __shared__ __align__(16) bf16 sB[128 * 64];
  int tiles_n = N >> 7;
  int bm = (int)blockIdx.x / tiles_n, bn = (int)blockIdx.x % tiles_n;
  int m0 = bm << 7, n0 = bn << 7;
  int tid = threadIdx.x, lane = tid & 63, w = tid >> 6;
  int wr = w >> 1, wc = w & 1;
  int l15 = lane & 15, lg = lane >> 4;
  int sr = lane >> 3, sc = lane & 7;

  f32x4 acc[4][4];
#pragma unroll
  for (int mf = 0; mf < 4; mf++)
#pragma unroll
    for (int nf = 0; nf < 4; nf++) acc[mf][nf] = (f32x4){0.f, 0.f, 0.f, 0.f};

  int nkt = K >> 6;
  for (int kt = 0; kt < nkt; kt++) {
    __syncthreads();
#pragma unroll
    for (int i = 0; i < 4; i++) {
      int iw = w * 4 + i;
      int row = iw * 8 + sr;
      gload_lds16(A + (size_t)(m0 + row) * K + kt * 64 + sc * 8, &sA[iw * 512]);
      gload_lds16(Bt + (size_t)(n0 + row) * K + kt * 64 + sc * 8, &sB[iw * 512]);
    }
    __syncthreads();
#pragma unroll
    for (int ks = 0; ks < 2; ks++) {
      bf16x8 af[4], bfr[4];
#pragma unroll
      for (int mf = 0; mf < 4; mf++)
        af[mf] = *(const bf16x8*)&sA[(wr * 64 + mf * 16 + l15) * 64 + ks * 32 + lg * 8];
#pragma unroll
      for (int nf = 0; nf < 4; nf++)
        bfr[nf] = *(const bf16x8*)&sB[(wc * 64 + nf * 16 + l15) * 64 + ks * 32 + lg * 8];
#pragma unroll
      for (int mf = 0; mf < 4; mf++)
#pragma unroll
        for (int nf = 0; nf < 4; nf++)
          acc[mf][nf] = MFMA_16x16x32(af[mf], bfr[nf], acc[mf][nf]);
    }
  }

#pragma unroll
  for (int mf = 0; mf < 4; mf++) {
#pragma unroll
    for (int nf = 0; nf < 4; nf++) {
      int col = n0 + wc * 64 + nf * 16 + l15;
      int row0 = m0 + wr * 64 + mf * 16 + lg * 4;
      float biasv = bias[col];
      float* out = (float*)Cout;
#pragma unroll
      for (int r = 0; r < 4; r++)
        out[(size_t)(row0 + r) * N + col] = acc[mf][nf][r] + biasv;
    }
  }
}

// ---------------------------------------------------------------------------
// Flash attention (unchanged from round 5): swapped-S^T, global_load_lds
// double-buffered K/V, 8 waves x 32 q-rows, XOR-swizzled both-sides staging.
// ---------------------------------------------------------------------------
__global__ __launch_bounds__(512, 2) void attn_kernel(const bf16* __restrict__ Q,
                                                      const bf16* __restrict__ Km,
                                                      const bf16* __restrict__ Vt,
                                                      bf16* __restrict__ inter) {
  __shared__ __align__(16) bf16 sK[2][64 * 192];
  __shared__ __align__(16) bf16 sV[2][192 * 64];
  __shared__ __align__(16) bf16 sPT[8 * 2 * 16 * 72];

  int i = blockIdx.x;
  int j = i >> 3;
  int bh = (i & 7) * 4 + (j >> 3);
  int qt = j & 7;
  int b = bh >> 4, h = bh & 15;
  int tid = threadIdx.x, lane = tid & 63, w = tid >> 6;
  int l15 = lane & 15, lg = lane >> 4;
  int swz = l15 & 7;

  const bf16* Qh = Q + (size_t)b * 2048 * 3072 + (size_t)h * 192;
  const bf16* Kh = Km + (size_t)b * 2048 * 3072 + (size_t)h * 192;
  const bf16* Vh = Vt + (size_t)bh * 192 * 2048;

  int q0 = qt * 256 + w * 32;

  int kOff[3], vOff[3], ldsOff[3];
#pragma unroll
  for (int ii = 0; ii < 3; ii++) {
    int r = ii * 8 + w;
    int s = r * 64 + lane;
    int krow = s / 24, kc = s % 24;
    int kcs = (kc & 24) | ((kc & 7) ^ (krow & 7));
    kOff[ii] = krow * 3072 + kcs * 8;
    int vrow = s >> 3, vc = s & 7;
    int vcs = vc ^ (vrow & 7);
    vOff[ii] = vrow * 2048 + vcs * 8;
    ldsOff[ii] = r * 512;
  }

#define STAGE(BUF, KT)                                                      \
  {                                                                         \
    int kb = (KT) * 64;                                                     \
    _Pragma("unroll") for (int ii = 0; ii < 3; ii++) {                      \
      gload_lds16(Kh + (size_t)kb * 3072 + kOff[ii], &sK[BUF][ldsOff[ii]]); \
      gload_lds16(Vh + kb + vOff[ii], &sV[BUF][ldsOff[ii]]);                \
    }                                                                       \
  }

  STAGE(0, 0);

  bf16x8 aq[2][6];
#pragma unroll
  for (int rf = 0; rf < 2; rf++)
#pragma unroll
    for (int kc = 0; kc < 6; kc++)
      aq[rf][kc] = *(const bf16x8*)(Qh + (size_t)(q0 + rf * 16 + l15) * 3072 + kc * 32 + lg * 8);

  f32x4 o[2][12];
#pragma unroll
  for (int rf = 0; rf < 2; rf++)
#pragma unroll
    for (int df = 0; df < 12; df++) o[rf][df] = (f32x4){0.f, 0.f, 0.f, 0.f};
  float mrow[2] = {-1e30f, -1e30f};
  float lrow[2] = {0.f, 0.f};

  const float scl2 = 0.03125f * 1.44269504f;

  bf16* myPT0 = &sPT[((w * 2 + 0) * 16 + l15) * 72];
  bf16* myPT1 = &sPT[((w * 2 + 1) * 16 + l15) * 72];

  __syncthreads();

  for (int kt = 0; kt < 32; kt++) {
    const bf16* kbuf = sK[kt & 1];
    const bf16* vbuf = sV[kt & 1];
    if (kt < 31) STAGE((kt & 1) ^ 1, kt + 1);

    f32x4 st[4][2];
#pragma unroll
    for (int kf = 0; kf < 4; kf++)
#pragma unroll
      for (int rf = 0; rf < 2; rf++) st[kf][rf] = (f32x4){0.f, 0.f, 0.f, 0.f};
    __builtin_amdgcn_s_setprio(1);
#pragma unroll
    for (int kc = 0; kc < 6; kc++) {
      int g = kc * 4 + lg;
      int cc = (g & 24) | ((g & 7) ^ swz);
#pragma unroll
      for (int kf = 0; kf < 4; kf++) {
        bf16x8 bk = *(const bf16x8*)&kbuf[(kf * 16 + l15) * 192 + cc * 8];
        st[kf][0] = MFMA_16x16x32(bk, aq[0][kc], st[kf][0]);
        st[kf][1] = MFMA_16x16x32(bk, aq[1][kc], st[kf][1]);
      }
    }
    __builtin_amdgcn_s_setprio(0);

#pragma unroll
    for (int rf = 0; rf < 2; rf++) {
      bf16* myPT = rf ? myPT1 : myPT0;
      float mk[4];
#pragma unroll
      for (int kf = 0; kf < 4; kf++)
        mk[kf] = fmaxf(fmaxf(st[kf][rf][0], st[kf][rf][1]),
                       fmaxf(st[kf][rf][2], st[kf][rf][3]));
      float pmx = fmaxf(fmaxf(mk[0], mk[1]), fmaxf(mk[2], mk[3]));
      pmx = fmaxf(pmx, __shfl_xor(pmx, 16));
      pmx = fmaxf(pmx, __shfl_xor(pmx, 32));
      float pms = pmx * scl2;

      float mn = mrow[rf];
      if (!__all(pms - mn <= 11.0f)) {
        mn = fmaxf(mn, pms);
        float corr = exp2f(mrow[rf] - mn);
        mrow[rf] = mn;
        lrow[rf] *= corr;
#pragma unroll
        for (int df = 0; df < 12; df++) o[rf][df] *= corr;
      }

      float skf[4];
#pragma unroll
      for (int kf = 0; kf < 4; kf++) {
        float e0 = exp2f(fmaf(st[kf][rf][0], scl2, -mn));
        float e1 = exp2f(fmaf(st[kf][rf][1], scl2, -mn));
        float e2 = exp2f(fmaf(st[kf][rf][2], scl2, -mn));
        float e3 = exp2f(fmaf(st[kf][rf][3], scl2, -mn));
        skf[kf] = (e0 + e1) + (e2 + e3);
        bf16x4 pk4 = {(bf16)e0, (bf16)e1, (bf16)e2, (bf16)e3};
        *(bf16x4*)&myPT[kf * 16 + 4 * lg] = pk4;
      }
      float rs = (skf[0] + skf[1]) + (skf[2] + skf[3]);
      rs += __shfl_xor(rs, 16);
      rs += __shfl_xor(rs, 32);
      lrow[rf] += rs;
    }

    bf16x8 pf[2][2];
#pragma unroll
    for (int rf = 0; rf < 2; rf++) {
      bf16* myPT = rf ? myPT1 : myPT0;
#pragma unroll
      for (int ks = 0; ks < 2; ks++)
        pf[rf][ks] = *(const bf16x8*)&myPT[ks * 32 + lg * 8];
    }

    __builtin_amdgcn_s_setprio(1);
#pragma unroll
    for (int ks = 0; ks < 2; ks++) {
      int cv = (ks * 4 + lg) ^ swz;
#pragma unroll
      for (int df = 0; df < 12; df++) {
        bf16x8 av = *(const bf16x8*)&vbuf[(df * 16 + l15) * 64 + cv * 8];
        o[0][df] = MFMA_16x16x32(av, pf[0][ks], o[0][df]);
        o[1][df] = MFMA_16x16x32(av, pf[1][ks], o[1][df]);
      }
    }
    __builtin_amdgcn_s_setprio(0);

    __syncthreads();
  }

#pragma unroll
  for (int rf = 0; rf < 2; rf++) {
    float inv = 1.0f / lrow[rf];
    size_t token = (size_t)b * 2048 + q0 + rf * 16 + l15;
    bf16* outp = inter + token * 3072 + h * 192 + lg * 4;
#pragma unroll
    for (int df = 0; df < 12; df++) {
      bf16x4 pk = {(bf16)(o[rf][df][0] * inv), (bf16)(o[rf][df][1] * inv),
                   (bf16)(o[rf][df][2] * inv), (bf16)(o[rf][df][3] * inv)};
      *(bf16x4*)(outp + df * 16) = pk;
    }
  }
#undef STAGE
}

// ---------------------------------------------------------------------------
extern "C" void kernel_launch(void* const* d_in, const int* in_sizes, int n_in,
                              void* d_out, int out_size, void* d_ws, size_t ws_size,
                              hipStream_t stream) {
  const float* X = (const float*)d_in[0];
  const float* q_w = (const float*)d_in[1];
  const float* q_b = (const float*)d_in[2];
  const float* k_w = (const float*)d_in[3];
  const float* k_b = (const float*)d_in[4];
  const float* v_w = (const float*)d_in[5];
  const float* v_b = (const float*)d_in[6];
  const float* o_w = (const float*)d_in[7];
  const float* o_b = (const float*)d_in[8];

  char* ws = (char*)d_ws;
  // Wqt/Wvt/Wkt are contiguous: together one [9216][1024] bf16 matrix.
  bf16* Xb  = (bf16*)(ws);                    //  8 MiB: X bf16 [4096][1024]
  bf16* Wqt = (bf16*)(ws + 8388608);          //  6 MiB: q_w^T [3072][1024]
  bf16* Wvt = (bf16*)(ws + 14680064);         //  6 MiB: v_w^T (-> k_mat)
  bf16* Wkt = (bf16*)(ws + 20971520);         //  6 MiB: k_w^T (-> v_mat)
  bf16* Wot = (bf16*)(ws + 27262976);         //  6 MiB: o_w^T [1024][3072]
  bf16* Qm  = (bf16*)(ws + 33554432);         // 24 MiB: Q [4096][3072]
  bf16* Km  = (bf16*)(ws + 58720256);         // 24 MiB: K-attn [4096][3072]
  bf16* Vtw = (bf16*)(ws + 83886080);         // 24 MiB: V-attn^T [32][192][2048]
  bf16* Im  = (bf16*)(ws + 109051904);        // 24 MiB: inter [4096][3072]

  cvt_x_kernel<<<4096, 256, 0, stream>>>(X, Xb);
  transpose_cvt_kernel<<<3072, 256, 0, stream>>>(q_w, Wqt, 1024, 3072);
  transpose_cvt_kernel<<<3072, 256, 0, stream>>>(v_w, Wvt, 1024, 3072);
  transpose_cvt_kernel<<<3072, 256, 0, stream>>>(k_w, Wkt, 1024, 3072);
  transpose_cvt_kernel<<<3072, 256, 0, stream>>>(o_w, Wot, 3072, 1024);

  // fused Q/K/V projection (quirk: seg1 = X@v_w+v_b -> Km, seg2 = X@k_w+k_b -> V)
  gemm_fused_qkv<<<576, 512, 0, stream>>>(Xb, Wqt, q_b, v_b, k_b, Qm, Km, Vtw);

  attn_kernel<<<256, 512, 0, stream>>>(Qm, Km, Vtw, Im);

  gemm_bf16_kernel<2><<<256, 256, 0, stream>>>(Im, Wot, o_b, d_out, 4096, 1024, 3072);
}

// Round 8
// 331.547 us; speedup vs baseline: 1.0080x; 1.0080x over previous
//
#include <hip/hip_runtime.h>
#include <cstdint>
#include <cstddef>

typedef __bf16 bf16;
typedef __attribute__((ext_vector_type(8))) __bf16 bf16x8;
typedef __attribute__((ext_vector_type(4))) __bf16 bf16x4;
typedef __attribute__((ext_vector_type(2))) __bf16 bf16x2;
typedef __attribute__((ext_vector_type(4))) float f32x4;

#define MFMA_16x16x32(a, b, c) __builtin_amdgcn_mfma_f32_16x16x32_bf16((a), (b), (c), 0, 0, 0)

__device__ __forceinline__ void gload_lds16(const void* g, void* l) {
  __builtin_amdgcn_global_load_lds((__attribute__((address_space(1))) void*)g,
                                   (__attribute__((address_space(3))) void*)l,
                                   16, 0, 0);
}

// ---------------------------------------------------------------------------
// fp32 -> bf16 convert (grid covers exactly n/4 elements, n = 4096*1024)
// ---------------------------------------------------------------------------
__global__ __launch_bounds__(256) void cvt_x_kernel(const float* __restrict__ in,
                                                    bf16* __restrict__ out) {
  int i = blockIdx.x * 256 + threadIdx.x;
  float4 v = ((const float4*)in)[i];
  bf16x4 o = {(bf16)v.x, (bf16)v.y, (bf16)v.z, (bf16)v.w};
  ((bf16x4*)out)[i] = o;
}

// ---------------------------------------------------------------------------
// transpose + convert: in fp32 [R][C] -> out bf16 [C][R]
// ---------------------------------------------------------------------------
__global__ __launch_bounds__(256) void transpose_cvt_kernel(const float* __restrict__ in,
                                                            bf16* __restrict__ out,
                                                            int R, int C) {
  __shared__ float tile[32][33];
  int tiles_c = C >> 5;
  int br = (int)blockIdx.x / tiles_c, bc = (int)blockIdx.x % tiles_c;
  int r0 = br << 5, c0 = bc << 5;
  int tr = threadIdx.x >> 5, tc = threadIdx.x & 31;
#pragma unroll
  for (int i = 0; i < 4; i++)
    tile[tr + 8 * i][tc] = in[(size_t)(r0 + tr + 8 * i) * C + c0 + tc];
  __syncthreads();
#pragma unroll
  for (int i = 0; i < 4; i++) {
    int oc = tr + 8 * i;
    out[(size_t)(c0 + oc) * R + r0 + tc] = (bf16)tile[tc][oc];
  }
}

// ---------------------------------------------------------------------------
// Fused QKV projection GEMM, 128x256 tile, 2-phase counted-vmcnt schedule.
// A [4096][1024] bf16; Bt [9216][1024] bf16 = Wq^T | Wv^T | Wk^T contiguous.
// Out: seg0 -> Qm (+q_b), seg1 -> Km (+v_b), seg2 -> Vt transposed (+k_b).
// 512 thr = 8 waves (2M x 4N), per-wave out 64x64 (acc[4][4] f32x4).
// Grid 1152 (32 bm x 36 bn) = 4.5 rounds at 1 block/CU -> 90% tail util.
// LDS [buf][khalf][rows][32] bf16, 96 KB total.  Chunk swizzle: 16B chunk c
// of row r stored at slot c ^ ((r>>1)&3) (involution; inverse on per-lane
// global source, forward on ds_read offset).  Derivation: 128B window = 2
// rows x 4 slots; the 8 lanes reading it hit 8 distinct 16B slots ->
// conflict-free ds_read_b128 (fixes round-7's 8-way conflict).
// Schedule per tile s: ph1 {RD kh0(s); stage kh0(s+1)[3] then kh1(s+1)[3];
// vmcnt(6) gates kh1(s); barrier; 16 MFMA}; ph2 {RD kh1(s); vmcnt(3) gates
// kh0(s+1); barrier; 16 MFMA}.  Wrap-stage at s=15 keeps counts uniform.
// ---------------------------------------------------------------------------
__global__ __launch_bounds__(512, 2) void gemm_fused_qkv(
    const bf16* __restrict__ A, const bf16* __restrict__ Bt,
    const float* __restrict__ q_b, const float* __restrict__ v_b,
    const float* __restrict__ k_b,
    bf16* __restrict__ Qm, bf16* __restrict__ Km, bf16* __restrict__ Vt) {
  constexpr int K = 1024, NT = 16;  // K-tiles of 64
  __shared__ __align__(16) bf16 sA[2][2][128 * 32];  // 32 KB
  __shared__ __align__(16) bf16 sB[2][2][256 * 32];  // 64 KB

  // 1152 blocks = 8 XCDs x 144; per XCD: 4 fixed bm, bn-sweep (L2: 8 bn
  // B-panels ~4 MB + 4 bm A-panels ~1 MB resident per dispatch round).
  int bid = blockIdx.x;
  int xcd = bid & 7, j = bid >> 3;
  int bm = xcd * 4 + (j & 3), bn = j >> 2;
  int m0 = bm << 7, n0 = bn << 8;

  int tid = threadIdx.x, lane = tid & 63, w = tid >> 6;
  int wr = w >> 2, wc = w & 3;
  int l15 = lane & 15, lg = lane >> 4;

  // staging: region = 16 rows x 4 chunks of 16B; inverse swizzle on source
  int srow = lane >> 2, schk = lane & 3;
  int swzS = schk ^ ((srow >> 1) & 3);
  const bf16* gA = A + (size_t)(m0 + w * 16 + srow) * K + swzS * 8;
  const bf16* gB = Bt + (size_t)(n0 + w * 32 + srow) * K + swzS * 8;

#define STAGE_A(BUF, KH, T) \
  gload_lds16(gA + (size_t)(T) * 64 + (KH) * 32, &sA[BUF][KH][w * 512]);
#define STAGE_B(BUF, KH, T)                                                \
  {                                                                        \
    _Pragma("unroll") for (int ii = 0; ii < 2; ii++)                       \
        gload_lds16(gB + (size_t)(ii * 16) * K + (T) * 64 + (KH) * 32,     \
                    &sB[BUF][KH][w * 1024 + ii * 512]);                    \
  }
#define VMCNT(N) asm volatile("s_waitcnt vmcnt(" #N ")" ::: "memory")
#define LGK0                                           \
  {                                                    \
    asm volatile("s_waitcnt lgkmcnt(0)" ::: "memory"); \
    __builtin_amdgcn_sched_barrier(0);                 \
  }

  // swizzled read offsets (forward swizzle)
  int slot = lg ^ ((l15 >> 1) & 3);
  int aOff = (wr * 64 + l15) * 32 + slot * 8;
  int bOff = (wc * 64 + l15) * 32 + slot * 8;

#define RD_A(BUF, KS)                                      \
  _Pragma("unroll") for (int mf = 0; mf < 4; mf++)         \
      a[mf] = *(const bf16x8*)&sA[BUF][KS][aOff + mf * 512];
#define RD_B(BUF, KS)                                      \
  _Pragma("unroll") for (int nf = 0; nf < 4; nf++)         \
      b[nf] = *(const bf16x8*)&sB[BUF][KS][bOff + nf * 512];
#define MFMA16                                                          \
  _Pragma("unroll") for (int mf = 0; mf < 4; mf++)                      \
      _Pragma("unroll") for (int nf = 0; nf < 4; nf++)                  \
          acc[mf][nf] = MFMA_16x16x32(a[mf], b[nf], acc[mf][nf]);

  f32x4 acc[4][4];
#pragma unroll
  for (int mf = 0; mf < 4; mf++)
#pragma unroll
    for (int nf = 0; nf < 4; nf++) acc[mf][nf] = (f32x4){0.f, 0.f, 0.f, 0.f};

  // prologue: kh0(0) [3 loads], kh1(0) [3 loads]; drain to kh0(0)
  STAGE_A(0, 0, 0);
  STAGE_B(0, 0, 0);
  STAGE_A(0, 1, 0);
  STAGE_B(0, 1, 0);
  VMCNT(3);
  __builtin_amdgcn_s_barrier();

#pragma unroll 2
  for (int s = 0; s < NT; s++) {
    int buf = s & 1, nbuf = buf ^ 1;
    int nxt = (s + 1) & (NT - 1);
    bf16x8 a[4], b[4];

    // ---- ph1: ks0
    RD_A(buf, 0);
    RD_B(buf, 0);
    STAGE_A(nbuf, 0, nxt);  // kh0(s+1): first 3 loads
    STAGE_B(nbuf, 0, nxt);
    STAGE_A(nbuf, 1, nxt);  // kh1(s+1): last 3 loads
    STAGE_B(nbuf, 1, nxt);
    VMCNT(6);  // kh1(s) landed (6 newer loads may fly)
    __builtin_amdgcn_s_barrier();
    LGK0;
    __builtin_amdgcn_s_setprio(1);
    MFMA16;
    __builtin_amdgcn_s_setprio(0);

    // ---- ph2: ks1
    RD_A(buf, 1);
    RD_B(buf, 1);
    VMCNT(3);  // kh0(s+1) landed (3 newer loads may fly)
    __builtin_amdgcn_s_barrier();
    LGK0;
    __builtin_amdgcn_s_setprio(1);
    MFMA16;
    __builtin_amdgcn_s_setprio(0);
  }

  // ---- epilogue: route by N-segment (block-uniform; seg = bn/12)
  int seg = bn / 12;
  int segbn = bn - seg * 12;
  const float* bias = seg == 0 ? q_b : (seg == 1 ? v_b : k_b);
  bf16* outQK = seg == 0 ? Qm : Km;
#pragma unroll
  for (int mf = 0; mf < 4; mf++) {
#pragma unroll
    for (int nf = 0; nf < 4; nf++) {
      int colL = segbn * 256 + wc * 64 + nf * 16 + l15;
      int row0 = m0 + wr * 64 + mf * 16 + lg * 4;
      float bv = bias[colL];
      if (seg < 2) {
#pragma unroll
        for (int r = 0; r < 4; r++)
          outQK[(size_t)(row0 + r) * 3072 + colL] = (bf16)(acc[mf][nf][r] + bv);
      } else {
        int hh = colL / 192, dd = colL % 192;
        int bi = row0 >> 11, nn = row0 & 2047;
        bf16x4 pk = {(bf16)(acc[mf][nf][0] + bv), (bf16)(acc[mf][nf][1] + bv),
                     (bf16)(acc[mf][nf][2] + bv), (bf16)(acc[mf][nf][3] + bv)};
        *(bf16x4*)(Vt + (((size_t)bi * 16 + hh) * 192 + dd) * 2048 + nn) = pk;
      }
    }
  }
#undef STAGE_A
#undef STAGE_B
#undef VMCNT
#undef LGK0
#undef RD_A
#undef RD_B
#undef MFMA16
}

// ---------------------------------------------------------------------------
// bf16 GEMM (m97 structure), used for the final output projection.
// C[m][n] = sum_k A[m][k] * Bt[n][k] + bias[n]; fp32 out [M][N].
// ---------------------------------------------------------------------------
template <int EPI>
__global__ __launch_bounds__(256, 2) void gemm_bf16_kernel(const bf16* __restrict__ A,
                                                           const bf16* __restrict__ Bt,
                                                           const float* __restrict__ bias,
                                                           void* __restrict__ Cout,
                                                           int M, int N, int K) {
  __shared__ __align__(16) bf16 sA[128 * 64];
  __shared__ __align__(16) bf16 sB[128 * 64];
  int tiles_n = N >> 7;
  int bm = (int)blockIdx.x / tiles_n, bn = (int)blockIdx.x % tiles_n;
  int m0 = bm << 7, n0 = bn << 7;
  int tid = threadIdx.x, lane = tid & 63, w = tid >> 6;
  int wr = w >> 1, wc = w & 1;
  int l15 = lane & 15, lg = lane >> 4;
  int sr = lane >> 3, sc = lane & 7;

  f32x4 acc[4][4];
#pragma unroll
  for (int mf = 0; mf < 4; mf++)
#pragma unroll
    for (int nf = 0; nf < 4; nf++) acc[mf][nf] = (f32x4){0.f, 0.f, 0.f, 0.f};

  int nkt = K >> 6;
  for (int kt = 0; kt < nkt; kt++) {
    __syncthreads();
#pragma unroll
    for (int i = 0; i < 4; i++) {
      int iw = w * 4 + i;
      int row = iw * 8 + sr;
      gload_lds16(A + (size_t)(m0 + row) * K + kt * 64 + sc * 8, &sA[iw * 512]);
      gload_lds16(Bt + (size_t)(n0 + row) * K + kt * 64 + sc * 8, &sB[iw * 512]);
    }
    __syncthreads();
#pragma unroll
    for (int ks = 0; ks < 2; ks++) {
      bf16x8 af[4], bfr[4];
#pragma unroll
      for (int mf = 0; mf < 4; mf++)
        af[mf] = *(const bf16x8*)&sA[(wr * 64 + mf * 16 + l15) * 64 + ks * 32 + lg * 8];
#pragma unroll
      for (int nf = 0; nf < 4; nf++)
        bfr[nf] = *(const bf16x8*)&sB[(wc * 64 + nf * 16 + l15) * 64 + ks * 32 + lg * 8];
#pragma unroll
      for (int mf = 0; mf < 4; mf++)
#pragma unroll
        for (int nf = 0; nf < 4; nf++)
          acc[mf][nf] = MFMA_16x16x32(af[mf], bfr[nf], acc[mf][nf]);
    }
  }

#pragma unroll
  for (int mf = 0; mf < 4; mf++) {
#pragma unroll
    for (int nf = 0; nf < 4; nf++) {
      int col = n0 + wc * 64 + nf * 16 + l15;
      int row0 = m0 + wr * 64 + mf * 16 + lg * 4;
      float biasv = bias[col];
      float* out = (float*)Cout;
#pragma unroll
      for (int r = 0; r < 4; r++)
        out[(size_t)(row0 + r) * N + col] = acc[mf][nf][r] + biasv;
    }
  }
}

// ---------------------------------------------------------------------------
// Flash attention (unchanged from round 5): swapped-S^T, global_load_lds
// double-buffered K/V, 8 waves x 32 q-rows, XOR-swizzled both-sides staging.
// ---------------------------------------------------------------------------
__global__ __launch_bounds__(512, 2) void attn_kernel(const bf16* __restrict__ Q,
                                                      const bf16* __restrict__ Km,
                                                      const bf16* __restrict__ Vt,
                                                      bf16* __restrict__ inter) {
  __shared__ __align__(16) bf16 sK[2][64 * 192];
  __shared__ __align__(16) bf16 sV[2][192 * 64];
  __shared__ __align__(16) bf16 sPT[8 * 2 * 16 * 72];

  int i = blockIdx.x;
  int j = i >> 3;
  int bh = (i & 7) * 4 + (j >> 3);
  int qt = j & 7;
  int b = bh >> 4, h = bh & 15;
  int tid = threadIdx.x, lane = tid & 63, w = tid >> 6;
  int l15 = lane & 15, lg = lane >> 4;
  int swz = l15 & 7;

  const bf16* Qh = Q + (size_t)b * 2048 * 3072 + (size_t)h * 192;
  const bf16* Kh = Km + (size_t)b * 2048 * 3072 + (size_t)h * 192;
  const bf16* Vh = Vt + (size_t)bh * 192 * 2048;

  int q0 = qt * 256 + w * 32;

  int kOff[3], vOff[3], ldsOff[3];
#pragma unroll
  for (int ii = 0; ii < 3; ii++) {
    int r = ii * 8 + w;
    int s = r * 64 + lane;
    int krow = s / 24, kc = s % 24;
    int kcs = (kc & 24) | ((kc & 7) ^ (krow & 7));
    kOff[ii] = krow * 3072 + kcs * 8;
    int vrow = s >> 3, vc = s & 7;
    int vcs = vc ^ (vrow & 7);
    vOff[ii] = vrow * 2048 + vcs * 8;
    ldsOff[ii] = r * 512;
  }

#define STAGE(BUF, KT)                                                      \
  {                                                                         \
    int kb = (KT) * 64;                                                     \
    _Pragma("unroll") for (int ii = 0; ii < 3; ii++) {                      \
      gload_lds16(Kh + (size_t)kb * 3072 + kOff[ii], &sK[BUF][ldsOff[ii]]); \
      gload_lds16(Vh + kb + vOff[ii], &sV[BUF][ldsOff[ii]]);                \
    }                                                                       \
  }

  STAGE(0, 0);

  bf16x8 aq[2][6];
#pragma unroll
  for (int rf = 0; rf < 2; rf++)
#pragma unroll
    for (int kc = 0; kc < 6; kc++)
      aq[rf][kc] = *(const bf16x8*)(Qh + (size_t)(q0 + rf * 16 + l15) * 3072 + kc * 32 + lg * 8);

  f32x4 o[2][12];
#pragma unroll
  for (int rf = 0; rf < 2; rf++)
#pragma unroll
    for (int df = 0; df < 12; df++) o[rf][df] = (f32x4){0.f, 0.f, 0.f, 0.f};
  float mrow[2] = {-1e30f, -1e30f};
  float lrow[2] = {0.f, 0.f};

  const float scl2 = 0.03125f * 1.44269504f;

  bf16* myPT0 = &sPT[((w * 2 + 0) * 16 + l15) * 72];
  bf16* myPT1 = &sPT[((w * 2 + 1) * 16 + l15) * 72];

  __syncthreads();

  for (int kt = 0; kt < 32; kt++) {
    const bf16* kbuf = sK[kt & 1];
    const bf16* vbuf = sV[kt & 1];
    if (kt < 31) STAGE((kt & 1) ^ 1, kt + 1);

    f32x4 st[4][2];
#pragma unroll
    for (int kf = 0; kf < 4; kf++)
#pragma unroll
      for (int rf = 0; rf < 2; rf++) st[kf][rf] = (f32x4){0.f, 0.f, 0.f, 0.f};
    __builtin_amdgcn_s_setprio(1);
#pragma unroll
    for (int kc = 0; kc < 6; kc++) {
      int g = kc * 4 + lg;
      int cc = (g & 24) | ((g & 7) ^ swz);
#pragma unroll
      for (int kf = 0; kf < 4; kf++) {
        bf16x8 bk = *(const bf16x8*)&kbuf[(kf * 16 + l15) * 192 + cc * 8];
        st[kf][0] = MFMA_16x16x32(bk, aq[0][kc], st[kf][0]);
        st[kf][1] = MFMA_16x16x32(bk, aq[1][kc], st[kf][1]);
      }
    }
    __builtin_amdgcn_s_setprio(0);

#pragma unroll
    for (int rf = 0; rf < 2; rf++) {
      bf16* myPT = rf ? myPT1 : myPT0;
      float mk[4];
#pragma unroll
      for (int kf = 0; kf < 4; kf++)
        mk[kf] = fmaxf(fmaxf(st[kf][rf][0], st[kf][rf][1]),
                       fmaxf(st[kf][rf][2], st[kf][rf][3]));
      float pmx = fmaxf(fmaxf(mk[0], mk[1]), fmaxf(mk[2], mk[3]));
      pmx = fmaxf(pmx, __shfl_xor(pmx, 16));
      pmx = fmaxf(pmx, __shfl_xor(pmx, 32));
      float pms = pmx * scl2;

      float mn = mrow[rf];
      if (!__all(pms - mn <= 11.0f)) {
        mn = fmaxf(mn, pms);
        float corr = exp2f(mrow[rf] - mn);
        mrow[rf] = mn;
        lrow[rf] *= corr;
#pragma unroll
        for (int df = 0; df < 12; df++) o[rf][df] *= corr;
      }

      float skf[4];
#pragma unroll
      for (int kf = 0; kf < 4; kf++) {
        float e0 = exp2f(fmaf(st[kf][rf][0], scl2, -mn));
        float e1 = exp2f(fmaf(st[kf][rf][1], scl2, -mn));
        float e2 = exp2f(fmaf(st[kf][rf][2], scl2, -mn));
        float e3 = exp2f(fmaf(st[kf][rf][3], scl2, -mn));
        skf[kf] = (e0 + e1) + (e2 + e3);
        bf16x4 pk4 = {(bf16)e0, (bf16)e1, (bf16)e2, (bf16)e3};
        *(bf16x4*)&myPT[kf * 16 + 4 * lg] = pk4;
      }
      float rs = (skf[0] + skf[1]) + (skf[2] + skf[3]);
      rs += __shfl_xor(rs, 16);
      rs += __shfl_xor(rs, 32);
      lrow[rf] += rs;
    }

    bf16x8 pf[2][2];
#pragma unroll
    for (int rf = 0; rf < 2; rf++) {
      bf16* myPT = rf ? myPT1 : myPT0;
#pragma unroll
      for (int ks = 0; ks < 2; ks++)
        pf[rf][ks] = *(const bf16x8*)&myPT[ks * 32 + lg * 8];
    }

    __builtin_amdgcn_s_setprio(1);
#pragma unroll
    for (int ks = 0; ks < 2; ks++) {
      int cv = (ks * 4 + lg) ^ swz;
#pragma unroll
      for (int df = 0; df < 12; df++) {
        bf16x8 av = *(const bf16x8*)&vbuf[(df * 16 + l15) * 64 + cv * 8];
        o[0][df] = MFMA_16x16x32(av, pf[0][ks], o[0][df]);
        o[1][df] = MFMA_16x16x32(av, pf[1][ks], o[1][df]);
      }
    }
    __builtin_amdgcn_s_setprio(0);

    __syncthreads();
  }

#pragma unroll
  for (int rf = 0; rf < 2; rf++) {
    float inv = 1.0f / lrow[rf];
    size_t token = (size_t)b * 2048 + q0 + rf * 16 + l15;
    bf16* outp = inter + token * 3072 + h * 192 + lg * 4;
#pragma unroll
    for (int df = 0; df < 12; df++) {
      bf16x4 pk = {(bf16)(o[rf][df][0] * inv), (bf16)(o[rf][df][1] * inv),
                   (bf16)(o[rf][df][2] * inv), (bf16)(o[rf][df][3] * inv)};
      *(bf16x4*)(outp + df * 16) = pk;
    }
  }
#undef STAGE
}

// ---------------------------------------------------------------------------
extern "C" void kernel_launch(void* const* d_in, const int* in_sizes, int n_in,
                              void* d_out, int out_size, void* d_ws, size_t ws_size,
                              hipStream_t stream) {
  const float* X = (const float*)d_in[0];
  const float* q_w = (const float*)d_in[1];
  const float* q_b = (const float*)d_in[2];
  const float* k_w = (const float*)d_in[3];
  const float* k_b = (const float*)d_in[4];
  const float* v_w = (const float*)d_in[5];
  const float* v_b = (const float*)d_in[6];
  const float* o_w = (const float*)d_in[7];
  const float* o_b = (const float*)d_in[8];

  char* ws = (char*)d_ws;
  // Wqt/Wvt/Wkt are contiguous: together one [9216][1024] bf16 matrix.
  bf16* Xb  = (bf16*)(ws);                    //  8 MiB: X bf16 [4096][1024]
  bf16* Wqt = (bf16*)(ws + 8388608);          //  6 MiB: q_w^T [3072][1024]
  bf16* Wvt = (bf16*)(ws + 14680064);         //  6 MiB: v_w^T (-> k_mat)
  bf16* Wkt = (bf16*)(ws + 20971520);         //  6 MiB: k_w^T (-> v_mat)
  bf16* Wot = (bf16*)(ws + 27262976);         //  6 MiB: o_w^T [1024][3072]
  bf16* Qm  = (bf16*)(ws + 33554432);         // 24 MiB: Q [4096][3072]
  bf16* Km  = (bf16*)(ws + 58720256);         // 24 MiB: K-attn [4096][3072]
  bf16* Vtw = (bf16*)(ws + 83886080);         // 24 MiB: V-attn^T [32][192][2048]
  bf16* Im  = (bf16*)(ws + 109051904);        // 24 MiB: inter [4096][3072]

  cvt_x_kernel<<<4096, 256, 0, stream>>>(X, Xb);
  transpose_cvt_kernel<<<3072, 256, 0, stream>>>(q_w, Wqt, 1024, 3072);
  transpose_cvt_kernel<<<3072, 256, 0, stream>>>(v_w, Wvt, 1024, 3072);
  transpose_cvt_kernel<<<3072, 256, 0, stream>>>(k_w, Wkt, 1024, 3072);
  transpose_cvt_kernel<<<3072, 256, 0, stream>>>(o_w, Wot, 3072, 1024);

  // fused Q/K/V projection (quirk: seg1 = X@v_w+v_b -> Km, seg2 = X@k_w+k_b -> V)
  gemm_fused_qkv<<<1152, 512, 0, stream>>>(Xb, Wqt, q_b, v_b, k_b, Qm, Km, Vtw);

  attn_kernel<<<256, 512, 0, stream>>>(Qm, Km, Vtw, Im);

  gemm_bf16_kernel<2><<<256, 256, 0, stream>>>(Im, Wot, o_b, d_out, 4096, 1024, 3072);
}

// Round 9
// 313.059 us; speedup vs baseline: 1.0675x; 1.0591x over previous
//
#include <hip/hip_runtime.h>
#include <cstdint>
#include <cstddef>

typedef __bf16 bf16;
typedef __attribute__((ext_vector_type(8))) __bf16 bf16x8;
typedef __attribute__((ext_vector_type(4))) __bf16 bf16x4;
typedef __attribute__((ext_vector_type(2))) __bf16 bf16x2;
typedef __attribute__((ext_vector_type(4))) float f32x4;

#define MFMA_16x16x32(a, b, c) __builtin_amdgcn_mfma_f32_16x16x32_bf16((a), (b), (c), 0, 0, 0)

__device__ __forceinline__ void gload_lds16(const void* g, void* l) {
  __builtin_amdgcn_global_load_lds((__attribute__((address_space(1))) void*)g,
                                   (__attribute__((address_space(3))) void*)l,
                                   16, 0, 0);
}

// ---------------------------------------------------------------------------
// fp32 -> bf16 convert (grid covers exactly n/4 elements, n = 4096*1024)
// ---------------------------------------------------------------------------
__global__ __launch_bounds__(256) void cvt_x_kernel(const float* __restrict__ in,
                                                    bf16* __restrict__ out) {
  int i = blockIdx.x * 256 + threadIdx.x;
  float4 v = ((const float4*)in)[i];
  bf16x4 o = {(bf16)v.x, (bf16)v.y, (bf16)v.z, (bf16)v.w};
  ((bf16x4*)out)[i] = o;
}

// ---------------------------------------------------------------------------
// transpose + convert: in fp32 [R][C] -> out bf16 [C][R]
// ---------------------------------------------------------------------------
__global__ __launch_bounds__(256) void transpose_cvt_kernel(const float* __restrict__ in,
                                                            bf16* __restrict__ out,
                                                            int R, int C) {
  __shared__ float tile[32][33];
  int tiles_c = C >> 5;
  int br = (int)blockIdx.x / tiles_c, bc = (int)blockIdx.x % tiles_c;
  int r0 = br << 5, c0 = bc << 5;
  int tr = threadIdx.x >> 5, tc = threadIdx.x & 31;
#pragma unroll
  for (int i = 0; i < 4; i++)
    tile[tr + 8 * i][tc] = in[(size_t)(r0 + tr + 8 * i) * C + c0 + tc];
  __syncthreads();
#pragma unroll
  for (int i = 0; i < 4; i++) {
    int oc = tr + 8 * i;
    out[(size_t)(c0 + oc) * R + r0 + tc] = (bf16)tile[tc][oc];
  }
}

// ---------------------------------------------------------------------------
// Fused QKV projection GEMM, 256x192 tile, true 8-phase-style schedule.
// A [4096][1024] bf16; Bt [9216][1024] bf16 = Wq^T | Wv^T | Wk^T contiguous.
// Out: seg0 -> Qm (+q_b), seg1 -> Km (+v_b), seg2 -> Vt transposed (+k_b).
// 512 thr = 8 waves (2M x 4N); per-wave out 128x48 (acc[8][3] f32x4).
// Grid 768 (16 bm x 48 bn) = exactly 3.0 rounds at 1 block/CU (112 KB LDS).
// LDS: A [dbuf][kh][256x32] chunk-swizzled (slot = lg ^ ((row>>1)&3));
//      B [dbuf][192x64] row-swizzled (slot = (ks*4+lg) ^ (row&7)).
// Both swizzles: inverse on per-lane global source, forward on ds_read (G21).
// Phase = {ds_reads; stage; [vmcnt]; barrier; lgkmcnt(0)+sched_barrier;
//          setprio(1); 12 MFMA; setprio(0); barrier}  -- 2 barriers/phase.
// Per-wave in-flight ledger (7 loads/K-tile: ph1 B(s+1)x3, ph2 A0(s+1)x2,
// ph3 A1(s+1)x2): vmcnt(5)@ph2 drains A1(s) one barrier before ph3's reads;
// vmcnt(2)@ph4 drains B(s+1)+A0(s+1) one barrier before next ph1's reads.
// ---------------------------------------------------------------------------
__global__ __launch_bounds__(512, 2) void gemm_fused_qkv(
    const bf16* __restrict__ A, const bf16* __restrict__ Bt,
    const float* __restrict__ q_b, const float* __restrict__ v_b,
    const float* __restrict__ k_b,
    bf16* __restrict__ Qm, bf16* __restrict__ Km, bf16* __restrict__ Vt) {
  constexpr int K = 1024, NT = 16;  // K-tiles of 64
  __shared__ __align__(16) bf16 sA[2][2][256 * 32];  // 64 KB
  __shared__ __align__(16) bf16 sB[2][192 * 64];     // 48 KB

  // 768 blocks = 8 XCDs x 96; per XCD 2 bm x 48 bn (bn-major: B-panel shared
  // by 2 concurrent blocks, A-panels L2-resident and reused 48x).
  int bid = blockIdx.x;
  int xcd = bid & 7, j = bid >> 3;
  int bm = xcd * 2 + (j & 1), bn = j >> 1;
  int m0 = bm << 8, n0 = bn * 192;

  int tid = threadIdx.x, lane = tid & 63, w = tid >> 6;
  int wr = w >> 2, wc = w & 3;
  int l15 = lane & 15, lg = lane >> 4;

  // A staging: region = 16 rows x 4 chunks of 16B; 2 regions/wave per kh.
  int sra = lane >> 2, sca = lane & 3;
  const bf16* gA = A + (size_t)(m0 + w * 32 + sra) * K + ((sca ^ ((sra >> 1) & 3)) * 8);
  // B staging: region = 8 rows x 8 chunks of 16B; 3 regions/wave (full BK).
  int srb = lane >> 3, scb = lane & 7;
  const bf16* gB = Bt + (size_t)(n0 + w * 24 + srb) * K + ((scb ^ srb) * 8);

#define STAGE_A2(BUF, KH, T)                                               \
  {                                                                        \
    _Pragma("unroll") for (int ii = 0; ii < 2; ii++)                       \
        gload_lds16(gA + (size_t)(ii * 16) * K + (T) * 64 + (KH) * 32,     \
                    &sA[BUF][KH][w * 1024 + ii * 512]);                    \
  }
#define STAGE_B3(BUF, T)                                                   \
  {                                                                        \
    _Pragma("unroll") for (int ii = 0; ii < 3; ii++)                       \
        gload_lds16(gB + (size_t)(ii * 8) * K + (T) * 64,                  \
                    &sB[BUF][(w * 3 + ii) * 512]);                         \
  }
#define VMCNT(N) asm volatile("s_waitcnt vmcnt(" #N ")" ::: "memory")
#define LGK0                                           \
  {                                                    \
    asm volatile("s_waitcnt lgkmcnt(0)" ::: "memory"); \
    __builtin_amdgcn_sched_barrier(0);                 \
  }

  // read offsets (forward swizzle)
  int slotA = lg ^ ((l15 >> 1) & 3);
  int aBase = wr * 4096 + l15 * 32 + slotA * 8;          // + mf*512, per kh
  int bBase = (wc * 48 + l15) * 64;                      // + nf*1024
  int sB0 = (lg ^ (l15 & 7)) * 8;                        // ks0 slot bytes/2
  int sB1 = ((4 + lg) ^ (l15 & 7)) * 8;                  // ks1

#define RD_A(BUF, KH, MFB)                                                 \
  _Pragma("unroll") for (int mf = 0; mf < 4; mf++)                         \
      a[mf] = *(const bf16x8*)&sA[BUF][KH][aBase + (MFB + mf) * 512];
#define RD_B(BUF, SLOT, BV)                                                \
  _Pragma("unroll") for (int nf = 0; nf < 3; nf++)                         \
      BV[nf] = *(const bf16x8*)&sB[BUF][bBase + nf * 1024 + (SLOT)];
#define MFMA12(MFB, BV)                                                    \
  _Pragma("unroll") for (int mf = 0; mf < 4; mf++)                         \
      _Pragma("unroll") for (int nf = 0; nf < 3; nf++)                     \
          acc[MFB + mf][nf] = MFMA_16x16x32(a[mf], BV[nf], acc[MFB + mf][nf]);

  f32x4 acc[8][3];
#pragma unroll
  for (int mf = 0; mf < 8; mf++)
#pragma unroll
    for (int nf = 0; nf < 3; nf++) acc[mf][nf] = (f32x4){0.f, 0.f, 0.f, 0.f};

  // prologue: B(0)x3, A0(0)x2, A1(0)x2; drain all but A1(0) before ph1 reads
  STAGE_B3(0, 0);
  STAGE_A2(0, 0, 0);
  STAGE_A2(0, 1, 0);
  VMCNT(2);
  __builtin_amdgcn_s_barrier();

#pragma unroll 2
  for (int s = 0; s < NT; s++) {
    int buf = s & 1, nbuf = buf ^ 1;
    int nxt = (s + 1) & (NT - 1);
    bf16x8 a[4], b0[3], b1[3];

    // ---- ph1: ks0, mf0-3; stage B(s+1)
    RD_A(buf, 0, 0);
    RD_B(buf, sB0, b0);
    STAGE_B3(nbuf, nxt);
    __builtin_amdgcn_s_barrier();
    LGK0;
    __builtin_amdgcn_s_setprio(1);
    MFMA12(0, b0);
    __builtin_amdgcn_s_setprio(0);
    __builtin_amdgcn_s_barrier();

    // ---- ph2: ks0, mf4-7; stage A0(s+1); vmcnt(5) drains A1(s) for ph3
    RD_A(buf, 0, 4);
    STAGE_A2(nbuf, 0, nxt);
    VMCNT(5);
    __builtin_amdgcn_s_barrier();
    LGK0;
    __builtin_amdgcn_s_setprio(1);
    MFMA12(4, b0);
    __builtin_amdgcn_s_setprio(0);
    __builtin_amdgcn_s_barrier();

    // ---- ph3: ks1, mf0-3; stage A1(s+1)
    RD_A(buf, 1, 0);
    RD_B(buf, sB1, b1);
    STAGE_A2(nbuf, 1, nxt);
    __builtin_amdgcn_s_barrier();
    LGK0;
    __builtin_amdgcn_s_setprio(1);
    MFMA12(0, b1);
    __builtin_amdgcn_s_setprio(0);
    __builtin_amdgcn_s_barrier();

    // ---- ph4: ks1, mf4-7; vmcnt(2) drains B(s+1)+A0(s+1) for next ph1
    RD_A(buf, 1, 4);
    VMCNT(2);
    __builtin_amdgcn_s_barrier();
    LGK0;
    __builtin_amdgcn_s_setprio(1);
    MFMA12(4, b1);
    __builtin_amdgcn_s_setprio(0);
    __builtin_amdgcn_s_barrier();
  }

  // ---- epilogue: route by N-segment (block-uniform; 3072 = 16 tiles x 192)
  int seg = bn >> 4;
  int segbn = bn & 15;
  const float* bias = seg == 0 ? q_b : (seg == 1 ? v_b : k_b);
  bf16* outQK = seg == 0 ? Qm : Km;
#pragma unroll
  for (int mf = 0; mf < 8; mf++) {
#pragma unroll
    for (int nf = 0; nf < 3; nf++) {
      int colL = segbn * 192 + wc * 48 + nf * 16 + l15;
      int row0 = m0 + wr * 128 + mf * 16 + lg * 4;
      float bv = bias[colL];
      if (seg < 2) {
#pragma unroll
        for (int r = 0; r < 4; r++)
          outQK[(size_t)(row0 + r) * 3072 + colL] = (bf16)(acc[mf][nf][r] + bv);
      } else {
        int hh = colL / 192, dd = colL % 192;
        int bi = row0 >> 11, nn = row0 & 2047;
        bf16x4 pk = {(bf16)(acc[mf][nf][0] + bv), (bf16)(acc[mf][nf][1] + bv),
                     (bf16)(acc[mf][nf][2] + bv), (bf16)(acc[mf][nf][3] + bv)};
        *(bf16x4*)(Vt + (((size_t)bi * 16 + hh) * 192 + dd) * 2048 + nn) = pk;
      }
    }
  }
#undef STAGE_A2
#undef STAGE_B3
#undef VMCNT
#undef LGK0
#undef RD_A
#undef RD_B
#undef MFMA12
}

// ---------------------------------------------------------------------------
// bf16 GEMM (m97 structure), used for the final output projection.
// C[m][n] = sum_k A[m][k] * Bt[n][k] + bias[n]; fp32 out [M][N].
// ---------------------------------------------------------------------------
template <int EPI>
__global__ __launch_bounds__(256, 2) void gemm_bf16_kernel(const bf16* __restrict__ A,
                                                           const bf16* __restrict__ Bt,
                                                           const float* __restrict__ bias,
                                                           void* __restrict__ Cout,
                                                           int M, int N, int K) {
  __shared__ __align__(16) bf16 sA[128 * 64];
  __shared__ __align__(16) bf16 sB[128 * 64];
  int tiles_n = N >> 7;
  int bm = (int)blockIdx.x / tiles_n, bn = (int)blockIdx.x % tiles_n;
  int m0 = bm << 7, n0 = bn << 7;
  int tid = threadIdx.x, lane = tid & 63, w = tid >> 6;
  int wr = w >> 1, wc = w & 1;
  int l15 = lane & 15, lg = lane >> 4;
  int sr = lane >> 3, sc = lane & 7;

  f32x4 acc[4][4];
#pragma unroll
  for (int mf = 0; mf < 4; mf++)
#pragma unroll
    for (int nf = 0; nf < 4; nf++) acc[mf][nf] = (f32x4){0.f, 0.f, 0.f, 0.f};

  int nkt = K >> 6;
  for (int kt = 0; kt < nkt; kt++) {
    __syncthreads();
#pragma unroll
    for (int i = 0; i < 4; i++) {
      int iw = w * 4 + i;
      int row = iw * 8 + sr;
      gload_lds16(A + (size_t)(m0 + row) * K + kt * 64 + sc * 8, &sA[iw * 512]);
      gload_lds16(Bt + (size_t)(n0 + row) * K + kt * 64 + sc * 8, &sB[iw * 512]);
    }
    __syncthreads();
#pragma unroll
    for (int ks = 0; ks < 2; ks++) {
      bf16x8 af[4], bfr[4];
#pragma unroll
      for (int mf = 0; mf < 4; mf++)
        af[mf] = *(const bf16x8*)&sA[(wr * 64 + mf * 16 + l15) * 64 + ks * 32 + lg * 8];
#pragma unroll
      for (int nf = 0; nf < 4; nf++)
        bfr[nf] = *(const bf16x8*)&sB[(wc * 64 + nf * 16 + l15) * 64 + ks * 32 + lg * 8];
#pragma unroll
      for (int mf = 0; mf < 4; mf++)
#pragma unroll
        for (int nf = 0; nf < 4; nf++)
          acc[mf][nf] = MFMA_16x16x32(af[mf], bfr[nf], acc[mf][nf]);
    }
  }

#pragma unroll
  for (int mf = 0; mf < 4; mf++) {
#pragma unroll
    for (int nf = 0; nf < 4; nf++) {
      int col = n0 + wc * 64 + nf * 16 + l15;
      int row0 = m0 + wr * 64 + mf * 16 + lg * 4;
      float biasv = bias[col];
      float* out = (float*)Cout;
#pragma unroll
      for (int r = 0; r < 4; r++)
        out[(size_t)(row0 + r) * N + col] = acc[mf][nf][r] + biasv;
    }
  }
}

// ---------------------------------------------------------------------------
// Flash attention (unchanged from round 5): swapped-S^T, global_load_lds
// double-buffered K/V, 8 waves x 32 q-rows, XOR-swizzled both-sides staging.
// ---------------------------------------------------------------------------
__global__ __launch_bounds__(512, 2) void attn_kernel(const bf16* __restrict__ Q,
                                                      const bf16* __restrict__ Km,
                                                      const bf16* __restrict__ Vt,
                                                      bf16* __restrict__ inter) {
  __shared__ __align__(16) bf16 sK[2][64 * 192];
  __shared__ __align__(16) bf16 sV[2][192 * 64];
  __shared__ __align__(16) bf16 sPT[8 * 2 * 16 * 72];

  int i = blockIdx.x;
  int j = i >> 3;
  int bh = (i & 7) * 4 + (j >> 3);
  int qt = j & 7;
  int b = bh >> 4, h = bh & 15;
  int tid = threadIdx.x, lane = tid & 63, w = tid >> 6;
  int l15 = lane & 15, lg = lane >> 4;
  int swz = l15 & 7;

  const bf16* Qh = Q + (size_t)b * 2048 * 3072 + (size_t)h * 192;
  const bf16* Kh = Km + (size_t)b * 2048 * 3072 + (size_t)h * 192;
  const bf16* Vh = Vt + (size_t)bh * 192 * 2048;

  int q0 = qt * 256 + w * 32;

  int kOff[3], vOff[3], ldsOff[3];
#pragma unroll
  for (int ii = 0; ii < 3; ii++) {
    int r = ii * 8 + w;
    int s = r * 64 + lane;
    int krow = s / 24, kc = s % 24;
    int kcs = (kc & 24) | ((kc & 7) ^ (krow & 7));
    kOff[ii] = krow * 3072 + kcs * 8;
    int vrow = s >> 3, vc = s & 7;
    int vcs = vc ^ (vrow & 7);
    vOff[ii] = vrow * 2048 + vcs * 8;
    ldsOff[ii] = r * 512;
  }

#define STAGE(BUF, KT)                                                      \
  {                                                                         \
    int kb = (KT) * 64;                                                     \
    _Pragma("unroll") for (int ii = 0; ii < 3; ii++) {                      \
      gload_lds16(Kh + (size_t)kb * 3072 + kOff[ii], &sK[BUF][ldsOff[ii]]); \
      gload_lds16(Vh + kb + vOff[ii], &sV[BUF][ldsOff[ii]]);                \
    }                                                                       \
  }

  STAGE(0, 0);

  bf16x8 aq[2][6];
#pragma unroll
  for (int rf = 0; rf < 2; rf++)
#pragma unroll
    for (int kc = 0; kc < 6; kc++)
      aq[rf][kc] = *(const bf16x8*)(Qh + (size_t)(q0 + rf * 16 + l15) * 3072 + kc * 32 + lg * 8);

  f32x4 o[2][12];
#pragma unroll
  for (int rf = 0; rf < 2; rf++)
#pragma unroll
    for (int df = 0; df < 12; df++) o[rf][df] = (f32x4){0.f, 0.f, 0.f, 0.f};
  float mrow[2] = {-1e30f, -1e30f};
  float lrow[2] = {0.f, 0.f};

  const float scl2 = 0.03125f * 1.44269504f;

  bf16* myPT0 = &sPT[((w * 2 + 0) * 16 + l15) * 72];
  bf16* myPT1 = &sPT[((w * 2 + 1) * 16 + l15) * 72];

  __syncthreads();

  for (int kt = 0; kt < 32; kt++) {
    const bf16* kbuf = sK[kt & 1];
    const bf16* vbuf = sV[kt & 1];
    if (kt < 31) STAGE((kt & 1) ^ 1, kt + 1);

    f32x4 st[4][2];
#pragma unroll
    for (int kf = 0; kf < 4; kf++)
#pragma unroll
      for (int rf = 0; rf < 2; rf++) st[kf][rf] = (f32x4){0.f, 0.f, 0.f, 0.f};
    __builtin_amdgcn_s_setprio(1);
#pragma unroll
    for (int kc = 0; kc < 6; kc++) {
      int g = kc * 4 + lg;
      int cc = (g & 24) | ((g & 7) ^ swz);
#pragma unroll
      for (int kf = 0; kf < 4; kf++) {
        bf16x8 bk = *(const bf16x8*)&kbuf[(kf * 16 + l15) * 192 + cc * 8];
        st[kf][0] = MFMA_16x16x32(bk, aq[0][kc], st[kf][0]);
        st[kf][1] = MFMA_16x16x32(bk, aq[1][kc], st[kf][1]);
      }
    }
    __builtin_amdgcn_s_setprio(0);

#pragma unroll
    for (int rf = 0; rf < 2; rf++) {
      bf16* myPT = rf ? myPT1 : myPT0;
      float mk[4];
#pragma unroll
      for (int kf = 0; kf < 4; kf++)
        mk[kf] = fmaxf(fmaxf(st[kf][rf][0], st[kf][rf][1]),
                       fmaxf(st[kf][rf][2], st[kf][rf][3]));
      float pmx = fmaxf(fmaxf(mk[0], mk[1]), fmaxf(mk[2], mk[3]));
      pmx = fmaxf(pmx, __shfl_xor(pmx, 16));
      pmx = fmaxf(pmx, __shfl_xor(pmx, 32));
      float pms = pmx * scl2;

      float mn = mrow[rf];
      if (!__all(pms - mn <= 11.0f)) {
        mn = fmaxf(mn, pms);
        float corr = exp2f(mrow[rf] - mn);
        mrow[rf] = mn;
        lrow[rf] *= corr;
#pragma unroll
        for (int df = 0; df < 12; df++) o[rf][df] *= corr;
      }

      float skf[4];
#pragma unroll
      for (int kf = 0; kf < 4; kf++) {
        float e0 = exp2f(fmaf(st[kf][rf][0], scl2, -mn));
        float e1 = exp2f(fmaf(st[kf][rf][1], scl2, -mn));
        float e2 = exp2f(fmaf(st[kf][rf][2], scl2, -mn));
        float e3 = exp2f(fmaf(st[kf][rf][3], scl2, -mn));
        skf[kf] = (e0 + e1) + (e2 + e3);
        bf16x4 pk4 = {(bf16)e0, (bf16)e1, (bf16)e2, (bf16)e3};
        *(bf16x4*)&myPT[kf * 16 + 4 * lg] = pk4;
      }
      float rs = (skf[0] + skf[1]) + (skf[2] + skf[3]);
      rs += __shfl_xor(rs, 16);
      rs += __shfl_xor(rs, 32);
      lrow[rf] += rs;
    }

    bf16x8 pf[2][2];
#pragma unroll
    for (int rf = 0; rf < 2; rf++) {
      bf16* myPT = rf ? myPT1 : myPT0;
#pragma unroll
      for (int ks = 0; ks < 2; ks++)
        pf[rf][ks] = *(const bf16x8*)&myPT[ks * 32 + lg * 8];
    }

    __builtin_amdgcn_s_setprio(1);
#pragma unroll
    for (int ks = 0; ks < 2; ks++) {
      int cv = (ks * 4 + lg) ^ swz;
#pragma unroll
      for (int df = 0; df < 12; df++) {
        bf16x8 av = *(const bf16x8*)&vbuf[(df * 16 + l15) * 64 + cv * 8];
        o[0][df] = MFMA_16x16x32(av, pf[0][ks], o[0][df]);
        o[1][df] = MFMA_16x16x32(av, pf[1][ks], o[1][df]);
      }
    }
    __builtin_amdgcn_s_setprio(0);

    __syncthreads();
  }

#pragma unroll
  for (int rf = 0; rf < 2; rf++) {
    float inv = 1.0f / lrow[rf];
    size_t token = (size_t)b * 2048 + q0 + rf * 16 + l15;
    bf16* outp = inter + token * 3072 + h * 192 + lg * 4;
#pragma unroll
    for (int df = 0; df < 12; df++) {
      bf16x4 pk = {(bf16)(o[rf][df][0] * inv), (bf16)(o[rf][df][1] * inv),
                   (bf16)(o[rf][df][2] * inv), (bf16)(o[rf][df][3] * inv)};
      *(bf16x4*)(outp + df * 16) = pk;
    }
  }
#undef STAGE
}

// ---------------------------------------------------------------------------
extern "C" void kernel_launch(void* const* d_in, const int* in_sizes, int n_in,
                              void* d_out, int out_size, void* d_ws, size_t ws_size,
                              hipStream_t stream) {
  const float* X = (const float*)d_in[0];
  const float* q_w = (const float*)d_in[1];
  const float* q_b = (const float*)d_in[2];
  const float* k_w = (const float*)d_in[3];
  const float* k_b = (const float*)d_in[4];
  const float* v_w = (const float*)d_in[5];
  const float* v_b = (const float*)d_in[6];
  const float* o_w = (const float*)d_in[7];
  const float* o_b = (const float*)d_in[8];

  char* ws = (char*)d_ws;
  // Wqt/Wvt/Wkt are contiguous: together one [9216][1024] bf16 matrix.
  bf16* Xb  = (bf16*)(ws);                    //  8 MiB: X bf16 [4096][1024]
  bf16* Wqt = (bf16*)(ws + 8388608);          //  6 MiB: q_w^T [3072][1024]
  bf16* Wvt = (bf16*)(ws + 14680064);         //  6 MiB: v_w^T (-> k_mat)
  bf16* Wkt = (bf16*)(ws + 20971520);         //  6 MiB: k_w^T (-> v_mat)
  bf16* Wot = (bf16*)(ws + 27262976);         //  6 MiB: o_w^T [1024][3072]
  bf16* Qm  = (bf16*)(ws + 33554432);         // 24 MiB: Q [4096][3072]
  bf16* Km  = (bf16*)(ws + 58720256);         // 24 MiB: K-attn [4096][3072]
  bf16* Vtw = (bf16*)(ws + 83886080);         // 24 MiB: V-attn^T [32][192][2048]
  bf16* Im  = (bf16*)(ws + 109051904);        // 24 MiB: inter [4096][3072]

  cvt_x_kernel<<<4096, 256, 0, stream>>>(X, Xb);
  transpose_cvt_kernel<<<3072, 256, 0, stream>>>(q_w, Wqt, 1024, 3072);
  transpose_cvt_kernel<<<3072, 256, 0, stream>>>(v_w, Wvt, 1024, 3072);
  transpose_cvt_kernel<<<3072, 256, 0, stream>>>(k_w, Wkt, 1024, 3072);
  transpose_cvt_kernel<<<3072, 256, 0, stream>>>(o_w, Wot, 3072, 1024);

  // fused Q/K/V projection (quirk: seg1 = X@v_w+v_b -> Km, seg2 = X@k_w+k_b -> V)
  gemm_fused_qkv<<<768, 512, 0, stream>>>(Xb, Wqt, q_b, v_b, k_b, Qm, Km, Vtw);

  attn_kernel<<<256, 512, 0, stream>>>(Qm, Km, Vtw, Im);

  gemm_bf16_kernel<2><<<256, 256, 0, stream>>>(Im, Wot, o_b, d_out, 4096, 1024, 3072);
}